// Round 9
// baseline (2135.335 us; speedup 1.0000x reference)
//
#include <hip/hip_runtime.h>
#include <hip/hip_bf16.h>
#include <math.h>

#define H_DIM 2880
#define F_DIM 2880
#define GU_DIM 5760
#define NE 16
#define NT 1024
#define TOPK 4
#define NIT2 45           // K-steps (BK=64) for both GEMMs (H_DIM == F_DIM == 2880)

typedef float f32x4 __attribute__((ext_vector_type(4)));
typedef __bf16 bf16x8 __attribute__((ext_vector_type(8)));

__device__ __forceinline__ unsigned short f2bf(float f) {
    union { float f; unsigned u; } v; v.f = f;
    return (unsigned short)((v.u + 0x8000u) >> 16);   // round-half-up to bf16
}
__device__ __forceinline__ unsigned pk2(float a, float b) {
    return (unsigned)f2bf(a) | ((unsigned)f2bf(b) << 16);
}
// async global->LDS, 16B per lane; LDS dest is wave-uniform base + lane*16
__device__ __forceinline__ void gload16(const void* gsrc, void* ldst) {
    __builtin_amdgcn_global_load_lds(
        (const __attribute__((address_space(1))) unsigned int*)gsrc,
        (__attribute__((address_space(3))) unsigned int*)ldst,
        16, 0, 0);
}

// ---------------- x -> bf16 cast ----------------
__global__ __launch_bounds__(256) void castx_kernel(const float* __restrict__ x,
                                                    unsigned short* __restrict__ xb)
{
    int i = (blockIdx.x * 256 + threadIdx.x) * 8;
    float4 a = *(const float4*)(x + i);
    float4 b = *(const float4*)(x + i + 4);
    uint4 o;
    o.x = pk2(a.x, a.y); o.y = pk2(a.z, a.w);
    o.z = pk2(b.x, b.y); o.w = pk2(b.z, b.w);
    *(uint4*)(xb + i) = o;
}

// ---------------- router ----------------
__global__ __launch_bounds__(64) void router_kernel(
    const float* __restrict__ x, const float* __restrict__ rw, const float* __restrict__ rb,
    int* counts, int* topk_idx, float* topk_score)
{
    int t = blockIdx.x, lane = threadIdx.x;
    const float* xr = x + (size_t)t * H_DIM;
    float acc[NE];
#pragma unroll
    for (int e = 0; e < NE; e++) acc[e] = 0.f;
    for (int h = lane; h < H_DIM; h += 64) {
        float xv = xr[h];
#pragma unroll
        for (int e = 0; e < NE; e++) acc[e] += xv * rw[e * H_DIM + h];
    }
    float lg[NE];
#pragma unroll
    for (int e = 0; e < NE; e++) {
        float v = acc[e];
#pragma unroll
        for (int off = 32; off > 0; off >>= 1) v += __shfl_down(v, off, 64);
        lg[e] = v;
    }
    if (lane == 0) {
#pragma unroll
        for (int e = 0; e < NE; e++) lg[e] += rb[e];
        int mask = 0; float tv[TOPK]; int ti[TOPK];
        for (int k = 0; k < TOPK; k++) {
            float best = -1e30f; int bi = 0;
            for (int e = 0; e < NE; e++)
                if (!((mask >> e) & 1) && lg[e] > best) { best = lg[e]; bi = e; }
            mask |= 1 << bi; tv[k] = best; ti[k] = bi;
        }
        float m = tv[0], s = 0.f, ex[TOPK];
        for (int k = 0; k < TOPK; k++) { ex[k] = expf(tv[k] - m); s += ex[k]; }
        float inv = 1.f / s;
        for (int k = 0; k < TOPK; k++) {
            topk_idx[t * TOPK + k] = ti[k];
            topk_score[t * TOPK + k] = ex[k] * inv;
            atomicAdd(&counts[ti[k]], 1);
        }
    }
}

__global__ void offsets_kernel(const int* counts, int* offsets) {
    if (threadIdx.x == 0 && blockIdx.x == 0) {
        int s = 0;
        for (int e = 0; e < NE; e++) { offsets[e] = s; s += counts[e]; }
        offsets[NE] = s;
    }
}

__global__ void scatter_kernel(const int* topk_idx, const float* topk_score,
                               const int* offsets, int* fills, int* entry, float* entry_score,
                               int* slot_map)
{
    int t = blockIdx.x * blockDim.x + threadIdx.x;
    if (t >= NT) return;
    for (int k = 0; k < TOPK; k++) {
        int e = topk_idx[t * TOPK + k];
        int pos = atomicAdd(&fills[e], 1);
        int i = offsets[e] + pos;
        entry[i] = t | (k << 16);
        entry_score[i] = topk_score[t * TOPK + k];
        slot_map[t * TOPK + k] = i;
    }
}

// ===== GEMM machinery: tile 256m x 256n, BK=64 (= 2 x R8-proven 32-k halves),
// 16 waves / 1024 thr, LDS double-buffered, ONE barrier per 64-k step (45 steps).
// Per wave per step: 2 gload_lds (A halves) + 4 float4 (B: 1KB-contig rows) in
// flight under 32 MFMAs; explicit vmcnt(0) drain before the single barrier.
// Per-half layouts/swizzles byte-identical to round-8 (verified).

// B write address within a half: col n = 4*lane + c; wave wv -> k-pair wv
__device__ __forceinline__ int mk_bwr(int lane, int c, int wv) {
    int n = 4 * lane + c;
    int sn = ((n >> 3) ^ (n >> 5)) & 3;
    return n * 40 + (((wv >> 2) ^ sn) * 8) + (wv & 3) * 2;
}

#define GEMM_MFMA_HALF(AP, BP)                                                \
    {                                                                         \
        bf16x8 af_[4], bq_[4];                                                \
        _Pragma("unroll") for (int i = 0; i < 4; i++)                         \
            af_[i] = *(const bf16x8*)&(AP)[a_rd[i]];                          \
        _Pragma("unroll") for (int i = 0; i < 4; i++)                         \
            bq_[i] = *(const bf16x8*)&(BP)[b_rd[i]];                          \
        _Pragma("unroll") for (int mi = 0; mi < 4; mi++)                      \
            _Pragma("unroll") for (int ni = 0; ni < 4; ni++)                  \
                acc[mi][ni] = __builtin_amdgcn_mfma_f32_16x16x32_bf16(        \
                    af_[mi], bq_[ni], acc[mi][ni], 0, 0, 0);                  \
    }

#define GEMM_ISSUE(BUF, KK)                                                   \
    {                                                                         \
        gload16(asrc + (KK), &As[BUF][0][aoff]);                              \
        gload16(asrc + (KK) + 32, &As[BUF][1][aoff]);                         \
        r0[0] = *(const float4*)(bp + (size_t)(KK) * bstride);                \
        r0[1] = *(const float4*)(bp + (size_t)((KK) + 1) * bstride);          \
        r1[0] = *(const float4*)(bp + (size_t)((KK) + 32) * bstride);         \
        r1[1] = *(const float4*)(bp + (size_t)((KK) + 33) * bstride);         \
        asm volatile("" ::: "memory");                                        \
    }

#define GEMM_BWRITE(BUF)                                                      \
    {                                                                         \
        *(unsigned*)&Bs[BUF][0][bwr0] = pk2(r0[0].x, r0[1].x);                \
        *(unsigned*)&Bs[BUF][0][bwr1] = pk2(r0[0].y, r0[1].y);                \
        *(unsigned*)&Bs[BUF][0][bwr2] = pk2(r0[0].z, r0[1].z);                \
        *(unsigned*)&Bs[BUF][0][bwr3] = pk2(r0[0].w, r0[1].w);                \
        *(unsigned*)&Bs[BUF][1][bwr0] = pk2(r1[0].x, r1[1].x);                \
        *(unsigned*)&Bs[BUF][1][bwr1] = pk2(r1[0].y, r1[1].y);                \
        *(unsigned*)&Bs[BUF][1][bwr2] = pk2(r1[0].z, r1[1].z);                \
        *(unsigned*)&Bs[BUF][1][bwr3] = pk2(r1[0].w, r1[1].w);                \
    }

#define GEMM_BARRIER()                                                        \
    asm volatile("s_waitcnt lgkmcnt(0)" ::: "memory");                        \
    __builtin_amdgcn_sched_barrier(0);                                        \
    __builtin_amdgcn_s_barrier();                                             \
    __builtin_amdgcn_sched_barrier(0);

// ---------------- GEMM1: act = GLU(x[tokens] @ gate_up_w[e] + b) ----------------
__global__ __launch_bounds__(1024, 1) void gemm1_kernel(
    const unsigned short* __restrict__ xb, const float* __restrict__ gw, const float* __restrict__ gb,
    const int* __restrict__ counts, const int* __restrict__ offsets,
    const int* __restrict__ entry, unsigned short* __restrict__ act)
{
    int e = blockIdx.z;
    int cnt = counts[e];
    int m0 = blockIdx.y * 256;
    if (m0 >= cnt) return;
    int n0 = blockIdx.x * 256;
    int off = offsets[e];

    __shared__ __align__(16) unsigned short As[2][2][256 * 32];  // 16KB x4
    __shared__ __align__(16) unsigned short Bs[2][2][256 * 40];  // 20KB x4
    __shared__ int toks[256];

    int tid = threadIdx.x;
    if (tid < 256) {
        int r = m0 + tid;
        toks[tid] = entry[off + (r < cnt ? r : 0)] & 0xFFFF;
    }
    __syncthreads();

    int wv = tid >> 6, lane = tid & 63;

    // A gload: wave wv stages rows 16*wv..16*wv+15 per half (1 inst/half)
    int ar = 16 * wv + (lane >> 2);
    int ac = lane & 3;
    const unsigned short* asrc = xb + (size_t)toks[ar] * H_DIM + 8 * (ac ^ ((ar >> 1) & 3));
    int aoff = (16 * wv) * 32;

    // B staging: wave wv = k-pair {2wv,2wv+1} within each 32-k half
    int bcol = n0 + 4 * lane;
    int ncc = (bcol < GU_DIM) ? bcol : (GU_DIM - 4);   // ragged guard (5760 % 256 = 128 -> none here, safe anyway)
    const float* bp = gw + (size_t)e * H_DIM * GU_DIM + (size_t)(2 * wv) * GU_DIM + ncc;
    const size_t bstride = GU_DIM;
    int bwr0 = mk_bwr(lane, 0, wv);
    int bwr1 = mk_bwr(lane, 1, wv);
    int bwr2 = mk_bwr(lane, 2, wv);
    int bwr3 = mk_bwr(lane, 3, wv);

    int wm = (wv & 3) * 64, wn = (wv >> 2) * 64;
    int r16 = lane & 15, q = lane >> 4;

    f32x4 acc[4][4] = {};
    int a_rd[4], b_rd[4];
#pragma unroll
    for (int i = 0; i < 4; i++) {
        int m = wm + i * 16 + r16;
        a_rd[i] = m * 32 + ((q ^ ((m >> 1) & 3)) * 8);
        int n = wn + i * 16 + r16;
        int sn = ((n >> 3) ^ (n >> 5)) & 3;
        b_rd[i] = n * 40 + ((q ^ sn) * 8);
    }

    float4 r0[2], r1[2];
    // prologue: stage step 0 into buffer 0
    GEMM_ISSUE(0, 0);
    asm volatile("s_waitcnt vmcnt(0)" ::: "memory");
    __builtin_amdgcn_sched_barrier(0);
    GEMM_BWRITE(0);
    GEMM_BARRIER();

    for (int t = 0; t < NIT2; t++) {
        int cur = t & 1, nxt = cur ^ 1;
        bool more = (t + 1 < NIT2);
        if (more) GEMM_ISSUE(nxt, (t + 1) * 64);
        GEMM_MFMA_HALF(As[cur][0], Bs[cur][0]);
        GEMM_MFMA_HALF(As[cur][1], Bs[cur][1]);
        if (more) {
            asm volatile("s_waitcnt vmcnt(0)" ::: "memory");
            __builtin_amdgcn_sched_barrier(0);
            GEMM_BWRITE(nxt);
            GEMM_BARRIER();
        }
    }

    // epilogue: bias + GLU (gate=even col, up=odd col), store bf16 act
    const float* gbp = gb + (size_t)e * GU_DIM;
#pragma unroll
    for (int ni = 0; ni < 4; ni++) {
        int col = n0 + wn + ni * 16 + r16;
        float bias = (col < GU_DIM) ? gbp[col] : 0.f;
#pragma unroll
        for (int mi = 0; mi < 4; mi++) {
#pragma unroll
            for (int r = 0; r < 4; r++) {
                float v = acc[mi][ni][r] + bias;
                float vo = __shfl_xor(v, 1, 64);
                float gate = (lane & 1) ? vo : v;
                float up   = (lane & 1) ? v  : vo;
                gate = fminf(gate, 7.0f);
                up = fminf(fmaxf(up, -7.0f), 7.0f);
                float glu = gate / (1.0f + expf(-1.702f * gate));
                float a = (up + 1.0f) * glu;
                int row = m0 + wm + mi * 16 + q * 4 + r;
                if (row < cnt && col < GU_DIM && !(lane & 1))
                    act[(size_t)(off + row) * F_DIM + (col >> 1)] = f2bf(a);
            }
        }
    }
}

// ---------------- GEMM2: slot_out = score * (act @ down_w[e] + db) ----------------
__global__ __launch_bounds__(1024, 1) void gemm2_kernel(
    const unsigned short* __restrict__ act, const float* __restrict__ dw, const float* __restrict__ db,
    const int* __restrict__ counts, const int* __restrict__ offsets,
    const float* __restrict__ entry_score, float* __restrict__ slot_out)
{
    int e = blockIdx.z;
    int cnt = counts[e];
    int m0 = blockIdx.y * 256;
    if (m0 >= cnt) return;
    int n0 = blockIdx.x * 256;
    int off = offsets[e];

    __shared__ __align__(16) unsigned short As[2][2][256 * 32];
    __shared__ __align__(16) unsigned short Bs[2][2][256 * 40];
    __shared__ float scs[256];

    int tid = threadIdx.x;
    if (tid < 256) {
        int r = m0 + tid;
        scs[tid] = entry_score[off + (r < cnt ? r : 0)];
    }
    __syncthreads();

    int wv = tid >> 6, lane = tid & 63;

    int ar = 16 * wv + (lane >> 2);
    int ac = lane & 3;
    const unsigned short* asrc = act + (size_t)(off + m0 + ar) * F_DIM + 8 * (ac ^ ((ar >> 1) & 3));
    int aoff = (16 * wv) * 32;

    int bcol = n0 + 4 * lane;
    int ncc = (bcol < H_DIM) ? bcol : (H_DIM - 4);    // ragged last n-tile (2880 % 256 = 64)
    const float* bp = dw + (size_t)e * F_DIM * H_DIM + (size_t)(2 * wv) * H_DIM + ncc;
    const size_t bstride = H_DIM;
    int bwr0 = mk_bwr(lane, 0, wv);
    int bwr1 = mk_bwr(lane, 1, wv);
    int bwr2 = mk_bwr(lane, 2, wv);
    int bwr3 = mk_bwr(lane, 3, wv);

    int wm = (wv & 3) * 64, wn = (wv >> 2) * 64;
    int r16 = lane & 15, q = lane >> 4;

    f32x4 acc[4][4] = {};
    int a_rd[4], b_rd[4];
#pragma unroll
    for (int i = 0; i < 4; i++) {
        int m = wm + i * 16 + r16;
        a_rd[i] = m * 32 + ((q ^ ((m >> 1) & 3)) * 8);
        int n = wn + i * 16 + r16;
        int sn = ((n >> 3) ^ (n >> 5)) & 3;
        b_rd[i] = n * 40 + ((q ^ sn) * 8);
    }

    float4 r0[2], r1[2];
    GEMM_ISSUE(0, 0);
    asm volatile("s_waitcnt vmcnt(0)" ::: "memory");
    __builtin_amdgcn_sched_barrier(0);
    GEMM_BWRITE(0);
    GEMM_BARRIER();

    for (int t = 0; t < NIT2; t++) {
        int cur = t & 1, nxt = cur ^ 1;
        bool more = (t + 1 < NIT2);
        if (more) GEMM_ISSUE(nxt, (t + 1) * 64);
        GEMM_MFMA_HALF(As[cur][0], Bs[cur][0]);
        GEMM_MFMA_HALF(As[cur][1], Bs[cur][1]);
        if (more) {
            asm volatile("s_waitcnt vmcnt(0)" ::: "memory");
            __builtin_amdgcn_sched_barrier(0);
            GEMM_BWRITE(nxt);
            GEMM_BARRIER();
        }
    }

    const float* dbp = db + (size_t)e * H_DIM;
#pragma unroll
    for (int ni = 0; ni < 4; ni++) {
        int col = n0 + wn + ni * 16 + r16;
        float bias = (col < H_DIM) ? dbp[col] : 0.f;
#pragma unroll
        for (int mi = 0; mi < 4; mi++) {
#pragma unroll
            for (int r = 0; r < 4; r++) {
                int lr = wm + mi * 16 + q * 4 + r;
                if (m0 + lr < cnt && col < H_DIM) {
                    float v = (acc[mi][ni][r] + bias) * scs[lr];
                    slot_out[(size_t)(off + m0 + lr) * H_DIM + col] = v;
                }
            }
        }
    }
}

// ---------------- gather: out[t] = sum of the token's 4 slot rows ----------------
__global__ __launch_bounds__(256) void gather_kernel(
    const float* __restrict__ slot_out, const int* __restrict__ slot_map,
    float* __restrict__ out)
{
    int t = blockIdx.x;
    int s0 = slot_map[t * TOPK + 0];
    int s1 = slot_map[t * TOPK + 1];
    int s2 = slot_map[t * TOPK + 2];
    int s3 = slot_map[t * TOPK + 3];
    const float* r0 = slot_out + (size_t)s0 * H_DIM;
    const float* r1 = slot_out + (size_t)s1 * H_DIM;
    const float* r2 = slot_out + (size_t)s2 * H_DIM;
    const float* r3 = slot_out + (size_t)s3 * H_DIM;
    float* op = out + (size_t)t * H_DIM;
    for (int h = threadIdx.x * 4; h < H_DIM; h += 1024) {
        f32x4 v = *(const f32x4*)(r0 + h) + *(const f32x4*)(r1 + h)
                + *(const f32x4*)(r2 + h) + *(const f32x4*)(r3 + h);
        *(f32x4*)(op + h) = v;
    }
}

// ---------------- launch ----------------
extern "C" void kernel_launch(void* const* d_in, const int* in_sizes, int n_in,
                              void* d_out, int out_size, void* d_ws, size_t ws_size,
                              hipStream_t stream)
{
    const float* x  = (const float*)d_in[0];
    const float* rw = (const float*)d_in[1];
    const float* rb = (const float*)d_in[2];
    const float* gw = (const float*)d_in[3];
    const float* gb = (const float*)d_in[4];
    const float* dw = (const float*)d_in[5];
    const float* db = (const float*)d_in[6];
    float* out = (float*)d_out;

    char* ws = (char*)d_ws;
    int*   counts      = (int*)(ws);
    int*   fills       = (int*)(ws + 64);
    int*   offsets     = (int*)(ws + 128);
    int*   topk_idx    = (int*)(ws + 256);
    float* topk_score  = (float*)(ws + 16640);
    int*   entry       = (int*)(ws + 33024);
    float* entry_score = (float*)(ws + 49408);
    int*   slot_map    = (int*)(ws + 65792);
    unsigned short* act = (unsigned short*)(ws + 131072);   // 4352 x 2880 bf16 (256-row slack for gload overread)
    unsigned short* xb  = (unsigned short*)(ws + 25198592); // 1024 x 2880 bf16
    float* slot_out     = (float*)(ws + 31096832);          // 4096 x 2880 f32

    hipMemsetAsync(ws, 0, 256, stream);   // counts + fills

    castx_kernel<<<1440, 256, 0, stream>>>(x, xb);
    router_kernel<<<NT, 64, 0, stream>>>(x, rw, rb, counts, topk_idx, topk_score);
    offsets_kernel<<<1, 32, 0, stream>>>(counts, offsets);
    scatter_kernel<<<4, 256, 0, stream>>>(topk_idx, topk_score, offsets, fills, entry, entry_score, slot_map);
    gemm1_kernel<<<dim3(23, 4, NE), 1024, 0, stream>>>(xb, gw, gb, counts, offsets, entry, act);
    gemm2_kernel<<<dim3(12, 4, NE), 1024, 0, stream>>>(act, dw, db, counts, offsets, entry_score, slot_out);
    gather_kernel<<<NT, 256, 0, stream>>>(slot_out, slot_map, out);
}